// Round 1
// baseline (53.373 us; speedup 1.0000x reference)
//
#include <hip/hip_runtime.h>
#include <math.h>

#define BATCH 16
#define TQL   2048
#define TKL   1024
#define DDEC  256
#define DENC  256
#define DATT  128
#define WIN   3

// workspace layout (floats):
//   kw : 48*128      @ 0
//   vw : 48*128      @ 6144
//   kq : 48*256      @ 12288
//   vo : 48*256      @ 24576
//   kb : 48          @ 36864
#define WS_KW 0
#define WS_VW (48*DATT)
#define WS_KQ (2*48*DATT)
#define WS_VO (WS_KQ + 48*DDEC)
#define WS_KB (WS_VO + 48*DDEC)

// ---------------------------------------------------------------------------
// Kernel A: kw[b][j][c] = keys[b][prev+j] . Wk[c] + bk[c]   (c < 128)
//           vw[b][j][c] = values[b][prev+j] . Wv[c] + bv[c]
// grid = 48 blocks (b*3+j), 256 threads
// ---------------------------------------------------------------------------
__global__ __launch_bounds__(256) void precompute_kv(
    const float* __restrict__ keys, const float* __restrict__ values,
    const float* __restrict__ Wk, const float* __restrict__ bk,
    const float* __restrict__ Wv, const float* __restrict__ bv,
    const int* __restrict__ pidx, float* __restrict__ ws)
{
    const int blk = blockIdx.x;            // 0..47
    const int b = blk / WIN, j = blk % WIN;
    const int prev = pidx[0];
    const int col = prev + j;
    const bool valid = (col >= 0) && (col < TKL);

    __shared__ float ksh[DENC];
    __shared__ float vsh[DENC];
    const int t = threadIdx.x;
    if (t < DENC) {
        size_t base = ((size_t)b * TKL + (valid ? col : 0)) * DENC + t;
        ksh[t] = valid ? keys[base]   : 0.0f;
        vsh[t] = valid ? values[base] : 0.0f;
    }
    __syncthreads();

    if (t < DATT) {
        const float4* wrow = (const float4*)(Wk + (size_t)t * DENC);
        float acc = 0.0f;
        #pragma unroll 8
        for (int k4 = 0; k4 < DENC / 4; ++k4) {
            float4 w = wrow[k4];
            acc += w.x * ksh[k4*4+0] + w.y * ksh[k4*4+1]
                 + w.z * ksh[k4*4+2] + w.w * ksh[k4*4+3];
        }
        ws[WS_KW + blk * DATT + t] = acc + bk[t];
    } else {
        const int c = t - DATT;
        const float4* wrow = (const float4*)(Wv + (size_t)c * DENC);
        float acc = 0.0f;
        #pragma unroll 8
        for (int k4 = 0; k4 < DENC / 4; ++k4) {
            float4 w = wrow[k4];
            acc += w.x * vsh[k4*4+0] + w.y * vsh[k4*4+1]
                 + w.z * vsh[k4*4+2] + w.w * vsh[k4*4+3];
        }
        ws[WS_VW + blk * DATT + c] = acc + bv[c];
    }
}

// ---------------------------------------------------------------------------
// Kernel B: kq[b][j][d] = sum_c kw[b][j][c] * Wq[c][d]        (d < 256)
//           vo[b][j][d] = sum_c vw[b][j][c] * Wo[d][c]
//           kb[b][j]    = sum_c kw[b][j][c] * bq[c]
// grid = 48 blocks, 256 threads
// ---------------------------------------------------------------------------
__global__ __launch_bounds__(256) void precompute_proj(
    const float* __restrict__ Wq, const float* __restrict__ bq,
    const float* __restrict__ Wo, float* __restrict__ ws)
{
    const int blk = blockIdx.x;            // 0..47
    const int t = threadIdx.x;

    __shared__ float kwsh[DATT];
    __shared__ float vwsh[DATT];
    if (t < DATT)            kwsh[t]        = ws[WS_KW + blk * DATT + t];
    else if (t < 2 * DATT)   vwsh[t - DATT] = ws[WS_VW + blk * DATT + (t - DATT)];
    __syncthreads();

    float accq = 0.0f, acco = 0.0f;
    const float4* worow = (const float4*)(Wo + (size_t)t * DATT);
    #pragma unroll 4
    for (int c4 = 0; c4 < DATT / 4; ++c4) {
        float4 w = worow[c4];
        acco += w.x * vwsh[c4*4+0] + w.y * vwsh[c4*4+1]
              + w.z * vwsh[c4*4+2] + w.w * vwsh[c4*4+3];
        accq += kwsh[c4*4+0] * Wq[(size_t)(c4*4+0) * DDEC + t]
              + kwsh[c4*4+1] * Wq[(size_t)(c4*4+1) * DDEC + t]
              + kwsh[c4*4+2] * Wq[(size_t)(c4*4+2) * DDEC + t]
              + kwsh[c4*4+3] * Wq[(size_t)(c4*4+3) * DDEC + t];
    }
    ws[WS_KQ + blk * DDEC + t] = accq;
    ws[WS_VO + blk * DDEC + t] = acco;

    if (t == 0) {
        float acc = 0.0f;
        for (int c = 0; c < DATT; ++c) acc += bq[c] * kwsh[c];
        ws[WS_KB + blk] = acc;
    }
}

// ---------------------------------------------------------------------------
// Kernel C: one 64-lane wave per query row.
//   s_j = qrow . kq[b][j] + kb[b][j]  -> 3-way softmax -> a_j
//   out_row = (32*(a0*vo0 + a1*vo1 + a2*vo2) + bo + qrow) * sqrt(0.5)
//   attn_row = zeros with a_j patched at cols prev+j
// ---------------------------------------------------------------------------
__device__ __forceinline__ float winval(int ww, float w0, float w1, float w2) {
    float v = (ww == 0) ? w0 : ((ww == 1) ? w1 : ((ww == 2) ? w2 : 0.0f));
    return (ww >= 0 && ww < WIN) ? v : 0.0f;
}

__global__ __launch_bounds__(256) void attn_main(
    const float* __restrict__ query, const float* __restrict__ bo,
    const int* __restrict__ pidx, const float* __restrict__ ws,
    float* __restrict__ out, float* __restrict__ attn)
{
    const float* kq = ws + WS_KQ;
    const float* vo = ws + WS_VO;
    const float* kb = ws + WS_KB;
    const int prev = pidx[0];

    const int lane = threadIdx.x & 63;
    const int wid  = threadIdx.x >> 6;
    const int wglob = blockIdx.x * 4 + wid;
    const int nwaves = gridDim.x * 4;

    const float CTX_SCALE = 32.0f;            // Tk * sqrt(1/Tk) = sqrt(1024)
    const float RSQ2 = 0.70710678118654752f;  // sqrt(0.5)

    const float4 bo4 = ((const float4*)bo)[lane];

    for (int row = wglob; row < BATCH * TQL; row += nwaves) {
        const int b = row >> 11;              // row / 2048
        const int base = b * WIN;

        const float4 q4 = ((const float4*)(query + (size_t)row * DDEC))[lane];

        const float4 k0 = ((const float4*)(kq + (size_t)(base + 0) * DDEC))[lane];
        const float4 k1 = ((const float4*)(kq + (size_t)(base + 1) * DDEC))[lane];
        const float4 k2 = ((const float4*)(kq + (size_t)(base + 2) * DDEC))[lane];

        float p0 = q4.x*k0.x + q4.y*k0.y + q4.z*k0.z + q4.w*k0.w;
        float p1 = q4.x*k1.x + q4.y*k1.y + q4.z*k1.z + q4.w*k1.w;
        float p2 = q4.x*k2.x + q4.y*k2.y + q4.z*k2.z + q4.w*k2.w;

        #pragma unroll
        for (int off = 32; off > 0; off >>= 1) {
            p0 += __shfl_xor(p0, off, 64);
            p1 += __shfl_xor(p1, off, 64);
            p2 += __shfl_xor(p2, off, 64);
        }

        float s0 = p0 + kb[base + 0];
        float s1 = p1 + kb[base + 1];
        float s2 = p2 + kb[base + 2];

        const bool v0 = (prev + 0 >= 0) && (prev + 0 < TKL);
        const bool v1 = (prev + 1 >= 0) && (prev + 1 < TKL);
        const bool v2 = (prev + 2 >= 0) && (prev + 2 < TKL);
        const float NEG = -3.0e38f;
        if (!v0) s0 = NEG;
        if (!v1) s1 = NEG;
        if (!v2) s2 = NEG;

        const float m = fmaxf(s0, fmaxf(s1, s2));
        const float e0 = v0 ? __expf(s0 - m) : 0.0f;
        const float e1 = v1 ? __expf(s1 - m) : 0.0f;
        const float e2 = v2 ? __expf(s2 - m) : 0.0f;
        const float inv = 1.0f / (e0 + e1 + e2);
        const float w0 = e0 * inv, w1 = e1 * inv, w2 = e2 * inv;

        const float4 x0 = ((const float4*)(vo + (size_t)(base + 0) * DDEC))[lane];
        const float4 x1 = ((const float4*)(vo + (size_t)(base + 1) * DDEC))[lane];
        const float4 x2 = ((const float4*)(vo + (size_t)(base + 2) * DDEC))[lane];

        float4 o;
        o.x = (CTX_SCALE * (w0*x0.x + w1*x1.x + w2*x2.x) + bo4.x + q4.x) * RSQ2;
        o.y = (CTX_SCALE * (w0*x0.y + w1*x1.y + w2*x2.y) + bo4.y + q4.y) * RSQ2;
        o.z = (CTX_SCALE * (w0*x0.z + w1*x1.z + w2*x2.z) + bo4.z + q4.z) * RSQ2;
        o.w = (CTX_SCALE * (w0*x0.w + w1*x1.w + w2*x2.w) + bo4.w + q4.w) * RSQ2;
        ((float4*)(out + (size_t)row * DDEC))[lane] = o;

        float4* arow = (float4*)(attn + (size_t)row * TKL);
        #pragma unroll
        for (int seg = 0; seg < 4; ++seg) {
            const int c0 = seg * 256 + lane * 4;
            float4 z;
            z.x = winval(c0 + 0 - prev, w0, w1, w2);
            z.y = winval(c0 + 1 - prev, w0, w1, w2);
            z.z = winval(c0 + 2 - prev, w0, w1, w2);
            z.w = winval(c0 + 3 - prev, w0, w1, w2);
            arow[seg * 64 + lane] = z;
        }
    }
}

extern "C" void kernel_launch(void* const* d_in, const int* in_sizes, int n_in,
                              void* d_out, int out_size, void* d_ws, size_t ws_size,
                              hipStream_t stream)
{
    const float* query  = (const float*)d_in[0];
    const float* keys   = (const float*)d_in[1];
    const float* values = (const float*)d_in[2];
    const float* Wq     = (const float*)d_in[3];
    const float* bq     = (const float*)d_in[4];
    const float* Wk     = (const float*)d_in[5];
    const float* bk     = (const float*)d_in[6];
    const float* Wv     = (const float*)d_in[7];
    const float* bv     = (const float*)d_in[8];
    const float* Wo     = (const float*)d_in[9];
    const float* bo     = (const float*)d_in[10];
    const int*   pidx   = (const int*)d_in[11];

    float* ws   = (float*)d_ws;
    float* out  = (float*)d_out;
    float* attn = out + (size_t)BATCH * TQL * DDEC;

    precompute_kv<<<48, 256, 0, stream>>>(keys, values, Wk, bk, Wv, bv, pidx, ws);
    precompute_proj<<<48, 256, 0, stream>>>(Wq, bq, Wo, ws);
    attn_main<<<2048, 256, 0, stream>>>(query, bo, pidx, ws, out, attn);
}

// Round 2
// 50.070 us; speedup vs baseline: 1.0660x; 1.0660x over previous
//
#include <hip/hip_runtime.h>
#include <math.h>

#define BATCH 16
#define TQL   2048
#define TKL   1024
#define DDEC  256
#define DENC  256
#define DATT  128
#define WIN   3

// workspace layout (floats):
//   kq : 48*256  @ 0       (Wq^T-folded keys:  s_j = q . kq + kb)
//   vo : 48*256  @ 12288   (Wo-folded values:  ctx@Wo^T = 32 * sum a_j vo_j)
//   kb : 48      @ 24576
#define WS_KQ 0
#define WS_VO (48*DDEC)
#define WS_KB (2*48*DDEC)

// ---------------------------------------------------------------------------
// Fused precompute: for each (b, j) block (48 total):
//   kw[c] = keys[b][prev+j] . Wk[c] + bk[c]        (c < 128, in LDS)
//   vw[c] = values[b][prev+j] . Wv[c] + bv[c]
//   kq[d] = sum_c kw[c] * Wq[c][d]                  (d < 256)
//   vo[d] = sum_c vw[c] * Wo[d][c]
//   kb    = sum_c kw[c] * bq[c]
// ---------------------------------------------------------------------------
__global__ __launch_bounds__(256) void precompute(
    const float* __restrict__ keys, const float* __restrict__ values,
    const float* __restrict__ Wk, const float* __restrict__ bk,
    const float* __restrict__ Wv, const float* __restrict__ bv,
    const float* __restrict__ Wq, const float* __restrict__ bq,
    const float* __restrict__ Wo, const int* __restrict__ pidx,
    float* __restrict__ ws)
{
    const int blk = blockIdx.x;            // 0..47
    const int b = blk / WIN, j = blk % WIN;
    const int prev = pidx[0];
    const int col = prev + j;
    const bool valid = (col >= 0) && (col < TKL);

    __shared__ float ksh[DENC];
    __shared__ float vsh[DENC];
    __shared__ float kwsh[DATT];
    __shared__ float vwsh[DATT];

    const int t = threadIdx.x;
    {
        size_t base = ((size_t)b * TKL + (valid ? col : 0)) * DENC + t;
        ksh[t] = valid ? keys[base]   : 0.0f;
        vsh[t] = valid ? values[base] : 0.0f;
    }
    __syncthreads();

    if (t < DATT) {
        const float4* wrow = (const float4*)(Wk + (size_t)t * DENC);
        float acc = 0.0f;
        #pragma unroll 8
        for (int k4 = 0; k4 < DENC / 4; ++k4) {
            float4 w = wrow[k4];
            acc += w.x * ksh[k4*4+0] + w.y * ksh[k4*4+1]
                 + w.z * ksh[k4*4+2] + w.w * ksh[k4*4+3];
        }
        kwsh[t] = acc + bk[t];
    } else {
        const int c = t - DATT;
        const float4* wrow = (const float4*)(Wv + (size_t)c * DENC);
        float acc = 0.0f;
        #pragma unroll 8
        for (int k4 = 0; k4 < DENC / 4; ++k4) {
            float4 w = wrow[k4];
            acc += w.x * vsh[k4*4+0] + w.y * vsh[k4*4+1]
                 + w.z * vsh[k4*4+2] + w.w * vsh[k4*4+3];
        }
        vwsh[c] = acc + bv[c];
    }
    __syncthreads();

    float accq = 0.0f, acco = 0.0f;
    const float4* worow = (const float4*)(Wo + (size_t)t * DATT);
    #pragma unroll 4
    for (int c4 = 0; c4 < DATT / 4; ++c4) {
        float4 w = worow[c4];
        acco += w.x * vwsh[c4*4+0] + w.y * vwsh[c4*4+1]
              + w.z * vwsh[c4*4+2] + w.w * vwsh[c4*4+3];
        accq += kwsh[c4*4+0] * Wq[(size_t)(c4*4+0) * DDEC + t]
              + kwsh[c4*4+1] * Wq[(size_t)(c4*4+1) * DDEC + t]
              + kwsh[c4*4+2] * Wq[(size_t)(c4*4+2) * DDEC + t]
              + kwsh[c4*4+3] * Wq[(size_t)(c4*4+3) * DDEC + t];
    }
    ws[WS_KQ + blk * DDEC + t] = accq;
    ws[WS_VO + blk * DDEC + t] = acco;

    if (t < 64) {
        float pb = bq[t] * kwsh[t] + bq[t + 64] * kwsh[t + 64];
        #pragma unroll
        for (int off = 32; off > 0; off >>= 1) pb += __shfl_xor(pb, off, 64);
        if (t == 0) ws[WS_KB + blk] = pb;
    }
}

// ---------------------------------------------------------------------------
// Main: 16-lane group per query row; 4 rows per wave, 16 rows per block.
// Zero-stores of the attn row are issued up-front (independent of compute);
// the 1-2 float4s intersecting the window are skipped and patched after
// softmax, so attn traffic never waits on the q-load chain.
// ---------------------------------------------------------------------------
__device__ __forceinline__ float winval(int ww, float w0, float w1, float w2) {
    float v = (ww == 0) ? w0 : ((ww == 1) ? w1 : ((ww == 2) ? w2 : 0.0f));
    return (ww >= 0 && ww < WIN) ? v : 0.0f;
}

__global__ __launch_bounds__(256) void attn_main(
    const float* __restrict__ query, const float* __restrict__ bo,
    const int* __restrict__ pidx, const float* __restrict__ ws,
    float* __restrict__ out, float* __restrict__ attn)
{
    const float* kq = ws + WS_KQ;
    const float* vo = ws + WS_VO;
    const float* kb = ws + WS_KB;
    const int prev = pidx[0];

    const int t    = threadIdx.x;
    const int lane = t & 63;
    const int wid  = t >> 6;
    const int g    = lane >> 4;          // group within wave (0..3)
    const int sub  = lane & 15;          // lane within group
    const int row  = blockIdx.x * 16 + wid * 4 + g;
    const int b    = row >> 11;          // row / 2048
    const int base = b * WIN;

    // ---- issue q loads first (longest latency) ----
    const float4* q4p = (const float4*)query + (size_t)row * 64;
    const float4 q0 = q4p[ 0 + sub];
    const float4 q1 = q4p[16 + sub];
    const float4 q2 = q4p[32 + sub];
    const float4 q3 = q4p[48 + sub];

    // ---- window float4 indices (uniform) ----
    int lo = prev < 0 ? 0 : prev;
    int hi = prev + (WIN - 1) > TKL - 1 ? TKL - 1 : prev + (WIN - 1);
    int f0 = -1, f1 = -1;
    if (lo <= hi) { f0 = lo >> 2; f1 = hi >> 2; }

    // ---- stream attn zeros now (no dependencies) ----
    float4* arow = (float4*)(attn + (size_t)row * TKL);
    const float4 z4 = make_float4(0.0f, 0.0f, 0.0f, 0.0f);
    #pragma unroll
    for (int s = 0; s < 16; ++s) {
        const int f = s * 16 + sub;
        if (f != f0 && f != f1) arow[f] = z4;
    }

    // ---- scores: 3 dots of length 256 across the 16-lane group ----
    const float4* kqp0 = (const float4*)kq + (size_t)(base + 0) * 64;
    const float4* kqp1 = (const float4*)kq + (size_t)(base + 1) * 64;
    const float4* kqp2 = (const float4*)kq + (size_t)(base + 2) * 64;

    float p0, p1, p2;
    {
        float4 k0, k1, k2;
        k0 = kqp0[ 0 + sub]; k1 = kqp1[ 0 + sub]; k2 = kqp2[ 0 + sub];
        p0  = q0.x*k0.x + q0.y*k0.y + q0.z*k0.z + q0.w*k0.w;
        p1  = q0.x*k1.x + q0.y*k1.y + q0.z*k1.z + q0.w*k1.w;
        p2  = q0.x*k2.x + q0.y*k2.y + q0.z*k2.z + q0.w*k2.w;
        k0 = kqp0[16 + sub]; k1 = kqp1[16 + sub]; k2 = kqp2[16 + sub];
        p0 += q1.x*k0.x + q1.y*k0.y + q1.z*k0.z + q1.w*k0.w;
        p1 += q1.x*k1.x + q1.y*k1.y + q1.z*k1.z + q1.w*k1.w;
        p2 += q1.x*k2.x + q1.y*k2.y + q1.z*k2.z + q1.w*k2.w;
        k0 = kqp0[32 + sub]; k1 = kqp1[32 + sub]; k2 = kqp2[32 + sub];
        p0 += q2.x*k0.x + q2.y*k0.y + q2.z*k0.z + q2.w*k0.w;
        p1 += q2.x*k1.x + q2.y*k1.y + q2.z*k1.z + q2.w*k1.w;
        p2 += q2.x*k2.x + q2.y*k2.y + q2.z*k2.z + q2.w*k2.w;
        k0 = kqp0[48 + sub]; k1 = kqp1[48 + sub]; k2 = kqp2[48 + sub];
        p0 += q3.x*k0.x + q3.y*k0.y + q3.z*k0.z + q3.w*k0.w;
        p1 += q3.x*k1.x + q3.y*k1.y + q3.z*k1.z + q3.w*k1.w;
        p2 += q3.x*k2.x + q3.y*k2.y + q3.z*k2.z + q3.w*k2.w;
    }
    #pragma unroll
    for (int off = 8; off > 0; off >>= 1) {       // 4-level reduce within group
        p0 += __shfl_xor(p0, off, 64);
        p1 += __shfl_xor(p1, off, 64);
        p2 += __shfl_xor(p2, off, 64);
    }

    float s0 = p0 + kb[base + 0];
    float s1 = p1 + kb[base + 1];
    float s2 = p2 + kb[base + 2];

    const bool v0 = (prev + 0 >= 0) && (prev + 0 < TKL);
    const bool v1 = (prev + 1 >= 0) && (prev + 1 < TKL);
    const bool v2 = (prev + 2 >= 0) && (prev + 2 < TKL);
    const float NEG = -3.0e38f;
    if (!v0) s0 = NEG;
    if (!v1) s1 = NEG;
    if (!v2) s2 = NEG;

    const float m  = fmaxf(s0, fmaxf(s1, s2));
    const float e0 = v0 ? __expf(s0 - m) : 0.0f;
    const float e1 = v1 ? __expf(s1 - m) : 0.0f;
    const float e2 = v2 ? __expf(s2 - m) : 0.0f;
    const float inv = 1.0f / (e0 + e1 + e2);
    const float w0 = e0 * inv, w1 = e1 * inv, w2 = e2 * inv;

    // ---- context + output projection (folded) ----
    const float CTX_SCALE = 32.0f;            // Tk * sqrt(1/Tk) = sqrt(1024)
    const float RSQ2 = 0.70710678118654752f;  // sqrt(0.5)

    const float4* vop0 = (const float4*)vo + (size_t)(base + 0) * 64;
    const float4* vop1 = (const float4*)vo + (size_t)(base + 1) * 64;
    const float4* vop2 = (const float4*)vo + (size_t)(base + 2) * 64;
    const float4* bo4p = (const float4*)bo;
    float4* orow = (float4*)(out + (size_t)row * DDEC);

    #pragma unroll
    for (int k = 0; k < 4; ++k) {
        const float4 x0 = vop0[k * 16 + sub];
        const float4 x1 = vop1[k * 16 + sub];
        const float4 x2 = vop2[k * 16 + sub];
        const float4 bb = bo4p[k * 16 + sub];
        const float4 qq = (k == 0) ? q0 : (k == 1) ? q1 : (k == 2) ? q2 : q3;
        float4 o;
        o.x = (CTX_SCALE * (w0*x0.x + w1*x1.x + w2*x2.x) + bb.x + qq.x) * RSQ2;
        o.y = (CTX_SCALE * (w0*x0.y + w1*x1.y + w2*x2.y) + bb.y + qq.y) * RSQ2;
        o.z = (CTX_SCALE * (w0*x0.z + w1*x1.z + w2*x2.z) + bb.z + qq.z) * RSQ2;
        o.w = (CTX_SCALE * (w0*x0.w + w1*x1.w + w2*x2.w) + bb.w + qq.w) * RSQ2;
        orow[k * 16 + sub] = o;
    }

    // ---- patch the window float4(s) ----
    if (f0 >= 0 && (f0 & 15) == sub) {
        const int c0 = f0 * 4;
        float4 pz;
        pz.x = winval(c0 + 0 - prev, w0, w1, w2);
        pz.y = winval(c0 + 1 - prev, w0, w1, w2);
        pz.z = winval(c0 + 2 - prev, w0, w1, w2);
        pz.w = winval(c0 + 3 - prev, w0, w1, w2);
        arow[f0] = pz;
    }
    if (f1 >= 0 && f1 != f0 && (f1 & 15) == sub) {
        const int c0 = f1 * 4;
        float4 pz;
        pz.x = winval(c0 + 0 - prev, w0, w1, w2);
        pz.y = winval(c0 + 1 - prev, w0, w1, w2);
        pz.z = winval(c0 + 2 - prev, w0, w1, w2);
        pz.w = winval(c0 + 3 - prev, w0, w1, w2);
        arow[f1] = pz;
    }
}

extern "C" void kernel_launch(void* const* d_in, const int* in_sizes, int n_in,
                              void* d_out, int out_size, void* d_ws, size_t ws_size,
                              hipStream_t stream)
{
    const float* query  = (const float*)d_in[0];
    const float* keys   = (const float*)d_in[1];
    const float* values = (const float*)d_in[2];
    const float* Wq     = (const float*)d_in[3];
    const float* bq     = (const float*)d_in[4];
    const float* Wk     = (const float*)d_in[5];
    const float* bk     = (const float*)d_in[6];
    const float* Wv     = (const float*)d_in[7];
    const float* bv     = (const float*)d_in[8];
    const float* Wo     = (const float*)d_in[9];
    const float* bo     = (const float*)d_in[10];
    const int*   pidx   = (const int*)d_in[11];

    float* ws   = (float*)d_ws;
    float* out  = (float*)d_out;
    float* attn = out + (size_t)BATCH * TQL * DDEC;

    precompute<<<48, 256, 0, stream>>>(keys, values, Wk, bk, Wv, bv,
                                       Wq, bq, Wo, pidx, ws);
    attn_main<<<BATCH * TQL / 16, 256, 0, stream>>>(query, bo, pidx, ws, out, attn);
}

// Round 3
// 41.945 us; speedup vs baseline: 1.2724x; 1.1937x over previous
//
#include <hip/hip_runtime.h>
#include <math.h>

#define BATCH 16
#define TQL   2048
#define TKL   1024
#define DDEC  256
#define DENC  256
#define DATT  128
#define WIN   3

// workspace layout (floats):
//   kq : 48*256  @ 0       (Wq^T-folded keys:  s_j = q . kq + kb)
//   vo : 48*256  @ 12288   (Wo-folded values:  ctx@Wo^T = 32 * sum a_j vo_j)
//   kb : 48      @ 24576
#define WS_KQ 0
#define WS_VO (48*DDEC)
#define WS_KB (2*48*DDEC)

#define NZBLK 2048   // zero-fill blocks; 134217728 B / 2048 = 65536 B per block

// ---------------------------------------------------------------------------
// Kernel 1: blocks 0..47 run the folded-weight precompute (L2-bound, ~4 us);
// blocks 48..2095 stream zeros over the whole attn output (pure-store phase,
// runs at fill-kernel rate ~7 TB/s). Precompute hides under the fill.
// ---------------------------------------------------------------------------
__global__ __launch_bounds__(256) void pre_and_zero(
    const float* __restrict__ keys, const float* __restrict__ values,
    const float* __restrict__ Wk, const float* __restrict__ bk,
    const float* __restrict__ Wv, const float* __restrict__ bv,
    const float* __restrict__ Wq, const float* __restrict__ bq,
    const float* __restrict__ Wo, const int* __restrict__ pidx,
    float* __restrict__ ws, float* __restrict__ attn)
{
    const int t = threadIdx.x;

    if (blockIdx.x >= 48) {
        // ---- pure zero-fill of attn ----
        const int zb = blockIdx.x - 48;
        float4* p = (float4*)attn + (size_t)zb * 4096;   // 4096 float4 per block
        const float4 z4 = make_float4(0.0f, 0.0f, 0.0f, 0.0f);
        #pragma unroll
        for (int i = 0; i < 16; ++i) p[i * 256 + t] = z4;
        return;
    }

    // ---- precompute for (b, j) = blockIdx ----
    const int blk = blockIdx.x;            // 0..47
    const int b = blk / WIN, j = blk % WIN;
    const int prev = pidx[0];
    const int col = prev + j;
    const bool valid = (col >= 0) && (col < TKL);

    __shared__ float ksh[DENC];
    __shared__ float vsh[DENC];
    __shared__ float kwsh[DATT];
    __shared__ float vwsh[DATT];

    {
        size_t base = ((size_t)b * TKL + (valid ? col : 0)) * DENC + t;
        ksh[t] = valid ? keys[base]   : 0.0f;
        vsh[t] = valid ? values[base] : 0.0f;
    }
    __syncthreads();

    if (t < DATT) {
        const float4* wrow = (const float4*)(Wk + (size_t)t * DENC);
        float acc = 0.0f;
        #pragma unroll 8
        for (int k4 = 0; k4 < DENC / 4; ++k4) {
            float4 w = wrow[k4];
            acc += w.x * ksh[k4*4+0] + w.y * ksh[k4*4+1]
                 + w.z * ksh[k4*4+2] + w.w * ksh[k4*4+3];
        }
        kwsh[t] = acc + bk[t];
    } else {
        const int c = t - DATT;
        const float4* wrow = (const float4*)(Wv + (size_t)c * DENC);
        float acc = 0.0f;
        #pragma unroll 8
        for (int k4 = 0; k4 < DENC / 4; ++k4) {
            float4 w = wrow[k4];
            acc += w.x * vsh[k4*4+0] + w.y * vsh[k4*4+1]
                 + w.z * vsh[k4*4+2] + w.w * vsh[k4*4+3];
        }
        vwsh[c] = acc + bv[c];
    }
    __syncthreads();

    float accq = 0.0f, acco = 0.0f;
    const float4* worow = (const float4*)(Wo + (size_t)t * DATT);
    #pragma unroll 4
    for (int c4 = 0; c4 < DATT / 4; ++c4) {
        float4 w = worow[c4];
        acco += w.x * vwsh[c4*4+0] + w.y * vwsh[c4*4+1]
              + w.z * vwsh[c4*4+2] + w.w * vwsh[c4*4+3];
        accq += kwsh[c4*4+0] * Wq[(size_t)(c4*4+0) * DDEC + t]
              + kwsh[c4*4+1] * Wq[(size_t)(c4*4+1) * DDEC + t]
              + kwsh[c4*4+2] * Wq[(size_t)(c4*4+2) * DDEC + t]
              + kwsh[c4*4+3] * Wq[(size_t)(c4*4+3) * DDEC + t];
    }
    ws[WS_KQ + blk * DDEC + t] = accq;
    ws[WS_VO + blk * DDEC + t] = acco;

    if (t < 64) {
        float pb = bq[t] * kwsh[t] + bq[t + 64] * kwsh[t + 64];
        #pragma unroll
        for (int off = 32; off > 0; off >>= 1) pb += __shfl_xor(pb, off, 64);
        if (t == 0) ws[WS_KB + blk] = pb;
    }
}

// ---------------------------------------------------------------------------
// Kernel 2: 16-lane group per query row; 4 rows/wave, 16 rows/block.
// Computes the out row and patches the 1-2 window float4s of the attn row
// (zeros already written by kernel 1; stream order guarantees no race).
// ---------------------------------------------------------------------------
__device__ __forceinline__ float winval(int ww, float w0, float w1, float w2) {
    float v = (ww == 0) ? w0 : ((ww == 1) ? w1 : ((ww == 2) ? w2 : 0.0f));
    return (ww >= 0 && ww < WIN) ? v : 0.0f;
}

__global__ __launch_bounds__(256) void attn_out(
    const float* __restrict__ query, const float* __restrict__ bo,
    const int* __restrict__ pidx, const float* __restrict__ ws,
    float* __restrict__ out, float* __restrict__ attn)
{
    const float* kq = ws + WS_KQ;
    const float* vo = ws + WS_VO;
    const float* kb = ws + WS_KB;
    const int prev = pidx[0];

    const int t    = threadIdx.x;
    const int lane = t & 63;
    const int wid  = t >> 6;
    const int g    = lane >> 4;          // group within wave (0..3)
    const int sub  = lane & 15;          // lane within group
    const int row  = blockIdx.x * 16 + wid * 4 + g;
    const int b    = row >> 11;          // row / 2048
    const int base = b * WIN;

    // ---- q loads first (longest latency) ----
    const float4* q4p = (const float4*)query + (size_t)row * 64;
    const float4 q0 = q4p[ 0 + sub];
    const float4 q1 = q4p[16 + sub];
    const float4 q2 = q4p[32 + sub];
    const float4 q3 = q4p[48 + sub];

    // ---- scores: 3 dots of length 256 across the 16-lane group ----
    const float4* kqp0 = (const float4*)kq + (size_t)(base + 0) * 64;
    const float4* kqp1 = (const float4*)kq + (size_t)(base + 1) * 64;
    const float4* kqp2 = (const float4*)kq + (size_t)(base + 2) * 64;

    float p0, p1, p2;
    {
        float4 k0, k1, k2;
        k0 = kqp0[ 0 + sub]; k1 = kqp1[ 0 + sub]; k2 = kqp2[ 0 + sub];
        p0  = q0.x*k0.x + q0.y*k0.y + q0.z*k0.z + q0.w*k0.w;
        p1  = q0.x*k1.x + q0.y*k1.y + q0.z*k1.z + q0.w*k1.w;
        p2  = q0.x*k2.x + q0.y*k2.y + q0.z*k2.z + q0.w*k2.w;
        k0 = kqp0[16 + sub]; k1 = kqp1[16 + sub]; k2 = kqp2[16 + sub];
        p0 += q1.x*k0.x + q1.y*k0.y + q1.z*k0.z + q1.w*k0.w;
        p1 += q1.x*k1.x + q1.y*k1.y + q1.z*k1.z + q1.w*k1.w;
        p2 += q1.x*k2.x + q1.y*k2.y + q1.z*k2.z + q1.w*k2.w;
        k0 = kqp0[32 + sub]; k1 = kqp1[32 + sub]; k2 = kqp2[32 + sub];
        p0 += q2.x*k0.x + q2.y*k0.y + q2.z*k0.z + q2.w*k0.w;
        p1 += q2.x*k1.x + q2.y*k1.y + q2.z*k1.z + q2.w*k1.w;
        p2 += q2.x*k2.x + q2.y*k2.y + q2.z*k2.z + q2.w*k2.w;
        k0 = kqp0[48 + sub]; k1 = kqp1[48 + sub]; k2 = kqp2[48 + sub];
        p0 += q3.x*k0.x + q3.y*k0.y + q3.z*k0.z + q3.w*k0.w;
        p1 += q3.x*k1.x + q3.y*k1.y + q3.z*k1.z + q3.w*k1.w;
        p2 += q3.x*k2.x + q3.y*k2.y + q3.z*k2.z + q3.w*k2.w;
    }
    #pragma unroll
    for (int off = 8; off > 0; off >>= 1) {       // 4-level reduce within group
        p0 += __shfl_xor(p0, off, 64);
        p1 += __shfl_xor(p1, off, 64);
        p2 += __shfl_xor(p2, off, 64);
    }

    float s0 = p0 + kb[base + 0];
    float s1 = p1 + kb[base + 1];
    float s2 = p2 + kb[base + 2];

    const bool v0 = (prev + 0 >= 0) && (prev + 0 < TKL);
    const bool v1 = (prev + 1 >= 0) && (prev + 1 < TKL);
    const bool v2 = (prev + 2 >= 0) && (prev + 2 < TKL);
    const float NEG = -3.0e38f;
    if (!v0) s0 = NEG;
    if (!v1) s1 = NEG;
    if (!v2) s2 = NEG;

    const float m  = fmaxf(s0, fmaxf(s1, s2));
    const float e0 = v0 ? __expf(s0 - m) : 0.0f;
    const float e1 = v1 ? __expf(s1 - m) : 0.0f;
    const float e2 = v2 ? __expf(s2 - m) : 0.0f;
    const float inv = 1.0f / (e0 + e1 + e2);
    const float w0 = e0 * inv, w1 = e1 * inv, w2 = e2 * inv;

    // ---- context + output projection (folded) ----
    const float CTX_SCALE = 32.0f;            // Tk * sqrt(1/Tk) = sqrt(1024)
    const float RSQ2 = 0.70710678118654752f;  // sqrt(0.5)

    const float4* vop0 = (const float4*)vo + (size_t)(base + 0) * 64;
    const float4* vop1 = (const float4*)vo + (size_t)(base + 1) * 64;
    const float4* vop2 = (const float4*)vo + (size_t)(base + 2) * 64;
    const float4* bo4p = (const float4*)bo;
    float4* orow = (float4*)(out + (size_t)row * DDEC);

    #pragma unroll
    for (int k = 0; k < 4; ++k) {
        const float4 x0 = vop0[k * 16 + sub];
        const float4 x1 = vop1[k * 16 + sub];
        const float4 x2 = vop2[k * 16 + sub];
        const float4 bb = bo4p[k * 16 + sub];
        const float4 qq = (k == 0) ? q0 : (k == 1) ? q1 : (k == 2) ? q2 : q3;
        float4 o;
        o.x = (CTX_SCALE * (w0*x0.x + w1*x1.x + w2*x2.x) + bb.x + qq.x) * RSQ2;
        o.y = (CTX_SCALE * (w0*x0.y + w1*x1.y + w2*x2.y) + bb.y + qq.y) * RSQ2;
        o.z = (CTX_SCALE * (w0*x0.z + w1*x1.z + w2*x2.z) + bb.z + qq.z) * RSQ2;
        o.w = (CTX_SCALE * (w0*x0.w + w1*x1.w + w2*x2.w) + bb.w + qq.w) * RSQ2;
        orow[k * 16 + sub] = o;
    }

    // ---- patch the window float4(s) in attn ----
    int lo = prev < 0 ? 0 : prev;
    int hi = prev + (WIN - 1) > TKL - 1 ? TKL - 1 : prev + (WIN - 1);
    if (lo <= hi) {
        const int f0 = lo >> 2, f1 = hi >> 2;
        float4* arow = (float4*)(attn + (size_t)row * TKL);
        if ((f0 & 15) == sub) {
            const int c0 = f0 * 4;
            float4 pz;
            pz.x = winval(c0 + 0 - prev, w0, w1, w2);
            pz.y = winval(c0 + 1 - prev, w0, w1, w2);
            pz.z = winval(c0 + 2 - prev, w0, w1, w2);
            pz.w = winval(c0 + 3 - prev, w0, w1, w2);
            arow[f0] = pz;
        }
        if (f1 != f0 && (f1 & 15) == sub) {
            const int c0 = f1 * 4;
            float4 pz;
            pz.x = winval(c0 + 0 - prev, w0, w1, w2);
            pz.y = winval(c0 + 1 - prev, w0, w1, w2);
            pz.z = winval(c0 + 2 - prev, w0, w1, w2);
            pz.w = winval(c0 + 3 - prev, w0, w1, w2);
            arow[f1] = pz;
        }
    }
}

extern "C" void kernel_launch(void* const* d_in, const int* in_sizes, int n_in,
                              void* d_out, int out_size, void* d_ws, size_t ws_size,
                              hipStream_t stream)
{
    const float* query  = (const float*)d_in[0];
    const float* keys   = (const float*)d_in[1];
    const float* values = (const float*)d_in[2];
    const float* Wq     = (const float*)d_in[3];
    const float* bq     = (const float*)d_in[4];
    const float* Wk     = (const float*)d_in[5];
    const float* bk     = (const float*)d_in[6];
    const float* Wv     = (const float*)d_in[7];
    const float* bv     = (const float*)d_in[8];
    const float* Wo     = (const float*)d_in[9];
    const float* bo     = (const float*)d_in[10];
    const int*   pidx   = (const int*)d_in[11];

    float* ws   = (float*)d_ws;
    float* out  = (float*)d_out;
    float* attn = out + (size_t)BATCH * TQL * DDEC;

    pre_and_zero<<<48 + NZBLK, 256, 0, stream>>>(keys, values, Wk, bk, Wv, bv,
                                                 Wq, bq, Wo, pidx, ws, attn);
    attn_out<<<BATCH * TQL / 16, 256, 0, stream>>>(query, bo, pidx, ws, out, attn);
}